// Round 6
// baseline (1192.961 us; speedup 1.0000x reference)
//
#include <hip/hip_runtime.h>

#define THREADS 256
#define MBLOCKS 1024          // co-resident by construction (see launch_bounds)
#define MCHUNK  1024          // scan chunk: 256 thr x 4 elements

typedef int   v4i __attribute__((ext_vector_type(4)));
typedef float v4f __attribute__((ext_vector_type(4)));

// ---------------------------------------------------------------------------
// Manual grid barrier (sense-reversing, generation counter). Requires all
// blocks co-resident: grid=1024, block=256, __launch_bounds__(256,4) ->
// VGPR<=128 -> 4 blocks/CU x 256 CU = 1024. Device-scope atomics + fences
// handle cross-XCD visibility.
__device__ __forceinline__ void gbar(unsigned* cnt, unsigned* gen, unsigned nb) {
    __syncthreads();
    __threadfence();                               // release our data
    if (threadIdx.x == 0) {
        unsigned g = __hip_atomic_load(gen, __ATOMIC_RELAXED, __HIP_MEMORY_SCOPE_AGENT);
        unsigned a = __hip_atomic_fetch_add(cnt, 1u, __ATOMIC_ACQ_REL, __HIP_MEMORY_SCOPE_AGENT);
        if (a == nb - 1u) {
            __hip_atomic_store(cnt, 0u, __ATOMIC_RELAXED, __HIP_MEMORY_SCOPE_AGENT);
            __hip_atomic_store(gen, g + 1u, __ATOMIC_RELEASE, __HIP_MEMORY_SCOPE_AGENT);
        } else {
            while (__hip_atomic_load(gen, __ATOMIC_ACQUIRE, __HIP_MEMORY_SCOPE_AGENT) == g)
                __builtin_amdgcn_s_sleep(1);
        }
    }
    __syncthreads();
    __threadfence();                               // acquire others' data
}

__global__ void __launch_bounds__(THREADS, 4)
mega(const float* __restrict__ weight, const float* __restrict__ bias,
     const float* __restrict__ residues, const float* __restrict__ attrs,
     const int* __restrict__ tpre, const int* __restrict__ tpost,
     const int* __restrict__ nop, float* __restrict__ out,
     float* __restrict__ delta, float* __restrict__ vnode,
     float* __restrict__ partials, unsigned* __restrict__ bar,
     int N, int T, int P) {
    __shared__ float wavesums[THREADS / 64];
    __shared__ float redsum[THREADS / 64];
    unsigned* cnt = bar;
    unsigned* gen = bar + 1;
    const int tid = blockIdx.x * THREADS + threadIdx.x;
    const int nthreads = MBLOCKS * THREADS;        // 262,144
    const int lane = threadIdx.x & 63, wid = threadIdx.x >> 6;

    // ---- P1: filtered = residues * sigmoid(attrs@w+b); scatter into delta.
    // tpre u tpost is a permutation of [0,2N): every slot written exactly once.
    {
        v4f w0 = *(const v4f*)weight;
        v4f w1 = *(const v4f*)(weight + 4);
        float b = bias[0];
        int u0 = tid * 2;
        if (u0 + 2 <= N) {
            float r0 = residues[u0], r1 = residues[u0 + 1];
            int pre0 = tpre[u0],  pre1 = tpre[u0 + 1];
            int pos0 = tpost[u0], pos1 = tpost[u0 + 1];
            v4f a00 = *(const v4f*)(attrs + (size_t)u0 * 8);
            v4f a01 = *(const v4f*)(attrs + (size_t)u0 * 8 + 4);
            v4f a10 = *(const v4f*)(attrs + (size_t)u0 * 8 + 8);
            v4f a11 = *(const v4f*)(attrs + (size_t)u0 * 8 + 12);
            float l0 = a00.x*w0.x + a00.y*w0.y + a00.z*w0.z + a00.w*w0.w +
                       a01.x*w1.x + a01.y*w1.y + a01.z*w1.z + a01.w*w1.w + b;
            float l1 = a10.x*w0.x + a10.y*w0.y + a10.z*w0.z + a10.w*w0.w +
                       a11.x*w1.x + a11.y*w1.y + a11.z*w1.z + a11.w*w1.w + b;
            float f0 = r0 / (1.0f + __expf(-l0));
            float f1 = r1 / (1.0f + __expf(-l1));
            delta[pre0] =  f0; delta[pre1] =  f1;
            delta[pos0] = -f0; delta[pos1] = -f1;
        } else {
            for (int u = u0; u < N; ++u) {
                float logit = b;
                #pragma unroll
                for (int k = 0; k < 8; ++k) logit += attrs[(size_t)u * 8 + k] * weight[k];
                float f = residues[u] / (1.0f + __expf(-logit));
                delta[tpre[u]]  =  f;
                delta[tpost[u]] = -f;
            }
        }
    }
    gbar(cnt, gen, MBLOCKS);

    // ---- P2: per-chunk partial sums (one chunk per block).
    const int numChunks = (T + MCHUNK - 1) / MCHUNK;   // 977 <= MBLOCKS
    if (blockIdx.x < (unsigned)numChunks) {
        int base = blockIdx.x * MCHUNK + threadIdx.x * 4;
        float s = 0.0f;
        if (base + 4 <= T) {
            v4f v = *(const v4f*)(delta + base);
            s = v.x + v.y + v.z + v.w;
        } else {
            for (int i = 0; i < 4; ++i)
                if (base + i < T) s += delta[base + i];
        }
        #pragma unroll
        for (int d = 32; d > 0; d >>= 1) s += __shfl_down(s, d, 64);
        if (lane == 0) wavesums[wid] = s;
        __syncthreads();
        if (threadIdx.x == 0)
            partials[blockIdx.x] = wavesums[0] + wavesums[1] + wavesums[2] + wavesums[3];
    }
    gbar(cnt, gen, MBLOCKS);

    // ---- P3+P4: each block folds its own chunk offset (reduce partials[0..c))
    // then rescans its chunk in place.
    if (blockIdx.x < (unsigned)numChunks) {
        float c = 0.0f;
        for (int i = threadIdx.x; i < (int)blockIdx.x; i += THREADS)
            c += partials[i];
        #pragma unroll
        for (int d = 32; d > 0; d >>= 1) c += __shfl_down(c, d, 64);
        if (lane == 0) redsum[wid] = c;

        int base = blockIdx.x * MCHUNK + threadIdx.x * 4;
        float v[4];
        bool full = (base + 4 <= T);
        if (full) {
            v4f t = *(const v4f*)(delta + base);
            v[0]=t.x; v[1]=t.y; v[2]=t.z; v[3]=t.w;
        } else {
            for (int i = 0; i < 4; ++i)
                v[i] = (base + i < T) ? delta[base + i] : 0.0f;
        }
        float run = 0.0f;
        #pragma unroll
        for (int i = 0; i < 4; ++i) { run += v[i]; v[i] = run; }
        float tot = run;
        float x = tot;
        #pragma unroll
        for (int d = 1; d < 64; d <<= 1) {
            float y = __shfl_up(x, d, 64);
            if (lane >= d) x += y;
        }
        if (lane == 63) wavesums[wid] = x;
        __syncthreads();
        float woff = 0.0f;
        #pragma unroll
        for (int i = 0; i < THREADS / 64; ++i)
            if (i < wid) woff += wavesums[i];
        float offset = redsum[0] + redsum[1] + redsum[2] + redsum[3];
        float add = (x - tot) + woff + offset;
        if (full) {
            v4f o = { v[0]+add, v[1]+add, v[2]+add, v[3]+add };
            *(v4f*)(delta + base) = o;
        } else {
            for (int i = 0; i < 4; ++i)
                if (base + i < T) delta[base + i] = v[i] + add;
        }
    }
    gbar(cnt, gen, MBLOCKS);

    // ---- P5: vnode[u] = ycum[tpre[u]].
    {
        int u0 = tid * 2;
        if (u0 + 2 <= N) {
            int t0 = tpre[u0], t1 = tpre[u0 + 1];
            float y0 = delta[t0], y1 = delta[t1];
            vnode[u0] = y0; vnode[u0 + 1] = y1;
        } else {
            for (int u = u0; u < N; ++u) vnode[u] = delta[tpre[u]];
        }
    }
    gbar(cnt, gen, MBLOCKS);

    // ---- P6: out[p] = vnode[nop[p]], 32 px/thread in 4 batches of 8.
    {
        int i = tid * 8;
        #pragma unroll
        for (int b = 0; b < 4; ++b, i += nthreads * 8) {
            if (i + 8 <= P) {
                v4i n0 = *(const v4i*)(nop + i);
                v4i n1 = *(const v4i*)(nop + i + 4);
                v4f o0 = { vnode[n0.x], vnode[n0.y], vnode[n0.z], vnode[n0.w] };
                v4f o1 = { vnode[n1.x], vnode[n1.y], vnode[n1.z], vnode[n1.w] };
                *(v4f*)(out + i)     = o0;
                *(v4f*)(out + i + 4) = o1;
            } else {
                for (int j = i; j < P; ++j) out[j] = vnode[nop[j]];
            }
        }
    }
}

// ===========================================================================
// Fallback multi-kernel path (proven round-5 pipeline) for small workspaces.
#define SCAN_THREADS 256
#define EPT 8
#define CHUNK (SCAN_THREADS * EPT)

__global__ void k1_filter_scatter(const float* __restrict__ attrs,
                                  const float* __restrict__ weight,
                                  const float* __restrict__ bias,
                                  const float* __restrict__ residues,
                                  const int* __restrict__ tpre,
                                  const int* __restrict__ tpost,
                                  float* __restrict__ delta, int N) {
    int u0 = (blockIdx.x * blockDim.x + threadIdx.x) * 2;
    v4f w0 = *(const v4f*)weight;
    v4f w1 = *(const v4f*)(weight + 4);
    float b = bias[0];
    if (u0 + 2 <= N) {
        float r0 = residues[u0], r1 = residues[u0 + 1];
        int pre0 = tpre[u0],  pre1 = tpre[u0 + 1];
        int pos0 = tpost[u0], pos1 = tpost[u0 + 1];
        v4f a00 = *(const v4f*)(attrs + (size_t)u0 * 8);
        v4f a01 = *(const v4f*)(attrs + (size_t)u0 * 8 + 4);
        v4f a10 = *(const v4f*)(attrs + (size_t)u0 * 8 + 8);
        v4f a11 = *(const v4f*)(attrs + (size_t)u0 * 8 + 12);
        float l0 = a00.x*w0.x + a00.y*w0.y + a00.z*w0.z + a00.w*w0.w +
                   a01.x*w1.x + a01.y*w1.y + a01.z*w1.z + a01.w*w1.w + b;
        float l1 = a10.x*w0.x + a10.y*w0.y + a10.z*w0.z + a10.w*w0.w +
                   a11.x*w1.x + a11.y*w1.y + a11.z*w1.z + a11.w*w1.w + b;
        float f0 = r0 / (1.0f + __expf(-l0));
        float f1 = r1 / (1.0f + __expf(-l1));
        delta[pre0] =  f0; delta[pre1] =  f1;
        delta[pos0] = -f0; delta[pos1] = -f1;
    } else {
        for (int u = u0; u < N; ++u) {
            float logit = b;
            #pragma unroll
            for (int k = 0; k < 8; ++k) logit += attrs[(size_t)u * 8 + k] * weight[k];
            float f = residues[u] / (1.0f + __expf(-logit));
            delta[tpre[u]]  =  f;
            delta[tpost[u]] = -f;
        }
    }
}

__global__ void k2_partials(const float* __restrict__ delta,
                            float* __restrict__ partials, int T) {
    __shared__ float sdata[SCAN_THREADS / 64];
    int base = blockIdx.x * CHUNK + threadIdx.x * EPT;
    float s = 0.0f;
    if (base + EPT <= T) {
        v4f v0 = *(const v4f*)(delta + base);
        v4f v1 = *(const v4f*)(delta + base + 4);
        s = v0.x + v0.y + v0.z + v0.w + v1.x + v1.y + v1.z + v1.w;
    } else {
        for (int i = 0; i < EPT; ++i)
            if (base + i < T) s += delta[base + i];
    }
    #pragma unroll
    for (int d = 32; d > 0; d >>= 1) s += __shfl_down(s, d, 64);
    int lane = threadIdx.x & 63, wid = threadIdx.x >> 6;
    if (lane == 0) sdata[wid] = s;
    __syncthreads();
    if (threadIdx.x == 0)
        partials[blockIdx.x] = sdata[0] + sdata[1] + sdata[2] + sdata[3];
}

__global__ void k4_scan_chunks(float* __restrict__ data,
                               const float* __restrict__ partials, int T) {
    __shared__ float wavesums[SCAN_THREADS / 64];
    __shared__ float redsum[SCAN_THREADS / 64];
    int lane = threadIdx.x & 63, wid = threadIdx.x >> 6;
    float c = 0.0f;
    for (int i = threadIdx.x; i < blockIdx.x; i += SCAN_THREADS)
        c += partials[i];
    #pragma unroll
    for (int d = 32; d > 0; d >>= 1) c += __shfl_down(c, d, 64);
    if (lane == 0) redsum[wid] = c;
    int base = blockIdx.x * CHUNK + threadIdx.x * EPT;
    float v[EPT];
    bool full = (base + EPT <= T);
    if (full) {
        v4f v0 = *(const v4f*)(data + base);
        v4f v1 = *(const v4f*)(data + base + 4);
        v[0]=v0.x; v[1]=v0.y; v[2]=v0.z; v[3]=v0.w;
        v[4]=v1.x; v[5]=v1.y; v[6]=v1.z; v[7]=v1.w;
    } else {
        for (int i = 0; i < EPT; ++i)
            v[i] = (base + i < T) ? data[base + i] : 0.0f;
    }
    float run = 0.0f;
    #pragma unroll
    for (int i = 0; i < EPT; ++i) { run += v[i]; v[i] = run; }
    float tot = run;
    float x = tot;
    #pragma unroll
    for (int d = 1; d < 64; d <<= 1) {
        float y = __shfl_up(x, d, 64);
        if (lane >= d) x += y;
    }
    if (lane == 63) wavesums[wid] = x;
    __syncthreads();
    float woff = 0.0f, offset = redsum[0] + redsum[1] + redsum[2] + redsum[3];
    #pragma unroll
    for (int i = 0; i < SCAN_THREADS / 64; ++i)
        if (i < wid) woff += wavesums[i];
    float add = (x - tot) + woff + offset;
    if (full) {
        v4f o0 = { v[0]+add, v[1]+add, v[2]+add, v[3]+add };
        v4f o1 = { v[4]+add, v[5]+add, v[6]+add, v[7]+add };
        *(v4f*)(data + base)     = o0;
        *(v4f*)(data + base + 4) = o1;
    } else {
        for (int i = 0; i < EPT; ++i)
            if (base + i < T) data[base + i] = v[i] + add;
    }
}

__global__ void k5_node_values(const float* __restrict__ ycum,
                               const int* __restrict__ tpre,
                               float* __restrict__ vnode, int N) {
    int u0 = (blockIdx.x * blockDim.x + threadIdx.x) * 2;
    if (u0 + 2 <= N) {
        int t0 = tpre[u0], t1 = tpre[u0 + 1];
        float y0 = ycum[t0], y1 = ycum[t1];
        vnode[u0] = y0; vnode[u0 + 1] = y1;
    } else {
        for (int u = u0; u < N; ++u) vnode[u] = ycum[tpre[u]];
    }
}

__global__ void k6_gather(const float* __restrict__ vnode,
                          const int* __restrict__ nop,
                          float* __restrict__ out, int P) {
    int i = (blockIdx.x * blockDim.x + threadIdx.x) * 8;
    if (i + 8 <= P) {
        v4i n0 = *(const v4i*)(nop + i);
        v4i n1 = *(const v4i*)(nop + i + 4);
        v4f o0 = { vnode[n0.x], vnode[n0.y], vnode[n0.z], vnode[n0.w] };
        v4f o1 = { vnode[n1.x], vnode[n1.y], vnode[n1.z], vnode[n1.w] };
        *(v4f*)(out + i)     = o0;
        *(v4f*)(out + i + 4) = o1;
    } else {
        for (; i < P; ++i) out[i] = vnode[nop[i]];
    }
}

extern "C" void kernel_launch(void* const* d_in, const int* in_sizes, int n_in,
                              void* d_out, int out_size, void* d_ws, size_t ws_size,
                              hipStream_t stream) {
    const float* weight   = (const float*)d_in[0];
    const float* bias     = (const float*)d_in[1];
    const float* residues = (const float*)d_in[2];
    const float* attrs    = (const float*)d_in[3];
    const int*   tpre     = (const int*)d_in[4];
    const int*   tpost    = (const int*)d_in[5];
    const int*   nop      = (const int*)d_in[6];
    float* out = (float*)d_out;

    const int N = in_sizes[2];        // 500,000
    const int T = 2 * N;              // 1,000,000
    const int P = out_size;           // 8,388,608

    // Mega path: delta(T) + vnode(N) + partials(1024) + barrier(64B).
    size_t megaNeed = ((size_t)T + N + 1024) * sizeof(float) + 64;

    if (ws_size >= megaNeed) {
        float* delta    = (float*)d_ws;
        float* vnode    = delta + T;
        float* partials = vnode + N;
        unsigned* bar   = (unsigned*)(partials + 1024);
        hipMemsetAsync(bar, 0, 64, stream);
        mega<<<MBLOCKS, THREADS, 0, stream>>>(
            weight, bias, residues, attrs, tpre, tpost, nop, out,
            delta, vnode, partials, bar, N, T, P);
        return;
    }

    // Fallback: proven 5-kernel pipeline.
    const int numChunks = (T + CHUNK - 1) / CHUNK;
    size_t needMid = (size_t)(N + 1024) * sizeof(float);
    float *delta, *vnode, *partials;
    if (ws_size >= needMid) {
        delta = out; vnode = (float*)d_ws; partials = vnode + N;
    } else {
        delta = out; vnode = nullptr; partials = (float*)d_ws;
    }
    k1_filter_scatter<<<(N / 2 + 255) / 256, 256, 0, stream>>>(
        attrs, weight, bias, residues, tpre, tpost, delta, N);
    k2_partials<<<numChunks, SCAN_THREADS, 0, stream>>>(delta, partials, T);
    k4_scan_chunks<<<numChunks, SCAN_THREADS, 0, stream>>>(delta, partials, T);
    k5_node_values<<<(N / 2 + 255) / 256, 256, 0, stream>>>(delta, tpre, vnode, N);
    k6_gather<<<(P / 8 + 255) / 256, 256, 0, stream>>>(vnode, nop, out, P);
}

// Round 7
// 224.318 us; speedup vs baseline: 5.3182x; 5.3182x over previous
//
#include <hip/hip_runtime.h>

#define SCAN_THREADS 256
#define EPT 8
#define CHUNK (SCAN_THREADS * EPT)   // 2048 elements per scan block

typedef int   v4i __attribute__((ext_vector_type(4)));
typedef float v4f __attribute__((ext_vector_type(4)));

// ---------------------------------------------------------------------------
// K1: filtered = residues * sigmoid(attrs @ w + b); scatter +/- into delta.
// tpre u tpost is a permutation of [0,2N) -> every slot written exactly once.
__global__ void k1_filter_scatter(const float* __restrict__ attrs,
                                  const float* __restrict__ weight,
                                  const float* __restrict__ bias,
                                  const float* __restrict__ residues,
                                  const int* __restrict__ tpre,
                                  const int* __restrict__ tpost,
                                  float* __restrict__ delta, int N) {
    int u0 = (blockIdx.x * blockDim.x + threadIdx.x) * 2;
    v4f w0 = *(const v4f*)weight;
    v4f w1 = *(const v4f*)(weight + 4);
    float b = bias[0];
    if (u0 + 2 <= N) {
        float r0 = residues[u0], r1 = residues[u0 + 1];
        int pre0 = tpre[u0],  pre1 = tpre[u0 + 1];
        int pos0 = tpost[u0], pos1 = tpost[u0 + 1];
        v4f a00 = *(const v4f*)(attrs + (size_t)u0 * 8);
        v4f a01 = *(const v4f*)(attrs + (size_t)u0 * 8 + 4);
        v4f a10 = *(const v4f*)(attrs + (size_t)u0 * 8 + 8);
        v4f a11 = *(const v4f*)(attrs + (size_t)u0 * 8 + 12);
        float l0 = a00.x*w0.x + a00.y*w0.y + a00.z*w0.z + a00.w*w0.w +
                   a01.x*w1.x + a01.y*w1.y + a01.z*w1.z + a01.w*w1.w + b;
        float l1 = a10.x*w0.x + a10.y*w0.y + a10.z*w0.z + a10.w*w0.w +
                   a11.x*w1.x + a11.y*w1.y + a11.z*w1.z + a11.w*w1.w + b;
        float f0 = r0 / (1.0f + __expf(-l0));
        float f1 = r1 / (1.0f + __expf(-l1));
        delta[pre0] =  f0; delta[pre1] =  f1;
        delta[pos0] = -f0; delta[pos1] = -f1;
    } else {
        for (int u = u0; u < N; ++u) {
            float logit = b;
            #pragma unroll
            for (int k = 0; k < 8; ++k) logit += attrs[(size_t)u * 8 + k] * weight[k];
            float f = residues[u] / (1.0f + __expf(-logit));
            delta[tpre[u]]  =  f;
            delta[tpost[u]] = -f;
        }
    }
}

// ---------------------------------------------------------------------------
// K2: per-chunk partial sums.
__global__ void k2_partials(const float* __restrict__ delta,
                            float* __restrict__ partials, int T) {
    __shared__ float sdata[SCAN_THREADS / 64];
    int base = blockIdx.x * CHUNK + threadIdx.x * EPT;
    float s = 0.0f;
    if (base + EPT <= T) {
        v4f v0 = *(const v4f*)(delta + base);
        v4f v1 = *(const v4f*)(delta + base + 4);
        s = v0.x + v0.y + v0.z + v0.w + v1.x + v1.y + v1.z + v1.w;
    } else {
        for (int i = 0; i < EPT; ++i)
            if (base + i < T) s += delta[base + i];
    }
    #pragma unroll
    for (int d = 32; d > 0; d >>= 1) s += __shfl_down(s, d, 64);
    int lane = threadIdx.x & 63, wid = threadIdx.x >> 6;
    if (lane == 0) sdata[wid] = s;
    __syncthreads();
    if (threadIdx.x == 0)
        partials[blockIdx.x] = sdata[0] + sdata[1] + sdata[2] + sdata[3];
}

// ---------------------------------------------------------------------------
// K4: in-place inclusive scan of each chunk; each block derives its own
// offset by reducing partials[0..blockIdx.x) (L2-hot, <=489 floats).
__global__ void k4_scan_chunks(float* __restrict__ data,
                               const float* __restrict__ partials, int T) {
    __shared__ float wavesums[SCAN_THREADS / 64];
    __shared__ float redsum[SCAN_THREADS / 64];
    int lane = threadIdx.x & 63, wid = threadIdx.x >> 6;
    float c = 0.0f;
    for (int i = threadIdx.x; i < blockIdx.x; i += SCAN_THREADS)
        c += partials[i];
    #pragma unroll
    for (int d = 32; d > 0; d >>= 1) c += __shfl_down(c, d, 64);
    if (lane == 0) redsum[wid] = c;
    int base = blockIdx.x * CHUNK + threadIdx.x * EPT;
    float v[EPT];
    bool full = (base + EPT <= T);
    if (full) {
        v4f v0 = *(const v4f*)(data + base);
        v4f v1 = *(const v4f*)(data + base + 4);
        v[0]=v0.x; v[1]=v0.y; v[2]=v0.z; v[3]=v0.w;
        v[4]=v1.x; v[5]=v1.y; v[6]=v1.z; v[7]=v1.w;
    } else {
        for (int i = 0; i < EPT; ++i)
            v[i] = (base + i < T) ? data[base + i] : 0.0f;
    }
    float run = 0.0f;
    #pragma unroll
    for (int i = 0; i < EPT; ++i) { run += v[i]; v[i] = run; }
    float tot = run;
    float x = tot;
    #pragma unroll
    for (int d = 1; d < 64; d <<= 1) {
        float y = __shfl_up(x, d, 64);
        if (lane >= d) x += y;
    }
    if (lane == 63) wavesums[wid] = x;
    __syncthreads();
    float woff = 0.0f, offset = redsum[0] + redsum[1] + redsum[2] + redsum[3];
    #pragma unroll
    for (int i = 0; i < SCAN_THREADS / 64; ++i)
        if (i < wid) woff += wavesums[i];
    float add = (x - tot) + woff + offset;
    if (full) {
        v4f o0 = { v[0]+add, v[1]+add, v[2]+add, v[3]+add };
        v4f o1 = { v[4]+add, v[5]+add, v[6]+add, v[7]+add };
        *(v4f*)(data + base)     = o0;
        *(v4f*)(data + base + 4) = o1;
    } else {
        for (int i = 0; i < EPT; ++i)
            if (base + i < T) data[base + i] = v[i] + add;
    }
}

// ---------------------------------------------------------------------------
// K6-direct: out[p] = ycum[tpre[nop[p]]] — k5 fused away. 8 px/thread,
// structured as 8 independent nop->tpre->ycum chains for latency overlap.
// tpre (2MB) and ycum (4MB) are L2-resident.
__global__ void k6_direct(const float* __restrict__ ycum,
                          const int* __restrict__ tpre,
                          const int* __restrict__ nop,
                          float* __restrict__ out, int P) {
    int i = (blockIdx.x * blockDim.x + threadIdx.x) * 8;
    if (i + 8 <= P) {
        v4i n0 = *(const v4i*)(nop + i);
        v4i n1 = *(const v4i*)(nop + i + 4);
        int t0 = tpre[n0.x], t1 = tpre[n0.y], t2 = tpre[n0.z], t3 = tpre[n0.w];
        int t4 = tpre[n1.x], t5 = tpre[n1.y], t6 = tpre[n1.z], t7 = tpre[n1.w];
        v4f o0 = { ycum[t0], ycum[t1], ycum[t2], ycum[t3] };
        v4f o1 = { ycum[t4], ycum[t5], ycum[t6], ycum[t7] };
        *(v4f*)(out + i)     = o0;
        *(v4f*)(out + i + 4) = o1;
    } else {
        for (; i < P; ++i) out[i] = ycum[tpre[nop[i]]];
    }
}

// ---------------------------------------------------------------------------
// Fallback tier kernels (delta aliases out -> need vnode indirection).
__global__ void k5_node_values(const float* __restrict__ ycum,
                               const int* __restrict__ tpre,
                               float* __restrict__ vnode, int N) {
    int u0 = (blockIdx.x * blockDim.x + threadIdx.x) * 2;
    if (u0 + 2 <= N) {
        int t0 = tpre[u0], t1 = tpre[u0 + 1];
        float y0 = ycum[t0], y1 = ycum[t1];
        vnode[u0] = y0; vnode[u0 + 1] = y1;
    } else {
        for (int u = u0; u < N; ++u) vnode[u] = ycum[tpre[u]];
    }
}

__global__ void k6_gather(const float* __restrict__ vnode,
                          const int* __restrict__ nop,
                          float* __restrict__ out, int P) {
    int i = (blockIdx.x * blockDim.x + threadIdx.x) * 8;
    if (i + 8 <= P) {
        v4i n0 = *(const v4i*)(nop + i);
        v4i n1 = *(const v4i*)(nop + i + 4);
        v4f o0 = { vnode[n0.x], vnode[n0.y], vnode[n0.z], vnode[n0.w] };
        v4f o1 = { vnode[n1.x], vnode[n1.y], vnode[n1.z], vnode[n1.w] };
        *(v4f*)(out + i)     = o0;
        *(v4f*)(out + i + 4) = o1;
    } else {
        for (; i < P; ++i) out[i] = vnode[nop[i]];
    }
}

extern "C" void kernel_launch(void* const* d_in, const int* in_sizes, int n_in,
                              void* d_out, int out_size, void* d_ws, size_t ws_size,
                              hipStream_t stream) {
    const float* weight   = (const float*)d_in[0];
    const float* bias     = (const float*)d_in[1];
    const float* residues = (const float*)d_in[2];
    const float* attrs    = (const float*)d_in[3];
    const int*   tpre     = (const int*)d_in[4];
    const int*   tpost    = (const int*)d_in[5];
    const int*   nop      = (const int*)d_in[6];
    float* out = (float*)d_out;

    const int N = in_sizes[2];        // 500,000
    const int T = 2 * N;              // 1,000,000
    const int P = out_size;           // 8,388,608
    const int numChunks = (T + CHUNK - 1) / CHUNK;   // 489

    size_t needMain = (size_t)(T + 1024) * sizeof(float);   // delta + partials
    size_t needMid  = (size_t)(N + 1024) * sizeof(float);   // vnode + partials

    if (ws_size >= needMain) {
        // 4-dispatch main path: k1 -> k2 -> k4 -> k6_direct.
        float* delta    = (float*)d_ws;
        float* partials = delta + T;
        k1_filter_scatter<<<(N / 2 + 255) / 256, 256, 0, stream>>>(
            attrs, weight, bias, residues, tpre, tpost, delta, N);
        k2_partials<<<numChunks, SCAN_THREADS, 0, stream>>>(delta, partials, T);
        k4_scan_chunks<<<numChunks, SCAN_THREADS, 0, stream>>>(delta, partials, T);
        k6_direct<<<(P / 8 + 255) / 256, 256, 0, stream>>>(delta, tpre, nop, out, P);
    } else {
        // Fallback: delta aliases out -> must materialize vnode before k6.
        float *delta = out, *vnode = (float*)d_ws, *partials = vnode + N;
        k1_filter_scatter<<<(N / 2 + 255) / 256, 256, 0, stream>>>(
            attrs, weight, bias, residues, tpre, tpost, delta, N);
        k2_partials<<<numChunks, SCAN_THREADS, 0, stream>>>(delta, partials, T);
        k4_scan_chunks<<<numChunks, SCAN_THREADS, 0, stream>>>(delta, partials, T);
        k5_node_values<<<(N / 2 + 255) / 256, 256, 0, stream>>>(delta, tpre, vnode, N);
        k6_gather<<<(P / 8 + 255) / 256, 256, 0, stream>>>(vnode, nop, out, P);
    }
}

// Round 8
// 170.392 us; speedup vs baseline: 7.0013x; 1.3165x over previous
//
#include <hip/hip_runtime.h>

typedef int   v4i __attribute__((ext_vector_type(4)));
typedef float v4f __attribute__((ext_vector_type(4)));

#define SCAN_THREADS 256
#define EPT 8
#define CHUNK (SCAN_THREADS * EPT)

#define NSEG   128
#define SEGLEN 8192          // 128 * 8192 = 1,048,576 >= T
#define SCHUNK 1024          // 256 threads x 4 elements per chunk pass

__device__ inline unsigned long long pack_sf(float v) {
    return (1ull << 32) | (unsigned long long)__float_as_uint(v);
}

// ---------------------------------------------------------------------------
// K1: filtered = residues * sigmoid(attrs @ w + b); scatter +/- into delta.
// tpre u tpost is a permutation of [0,2N) -> every slot written exactly once.
__global__ void k1_filter_scatter(const float* __restrict__ attrs,
                                  const float* __restrict__ weight,
                                  const float* __restrict__ bias,
                                  const float* __restrict__ residues,
                                  const int* __restrict__ tpre,
                                  const int* __restrict__ tpost,
                                  float* __restrict__ delta, int N) {
    int u0 = (blockIdx.x * blockDim.x + threadIdx.x) * 2;
    v4f w0 = *(const v4f*)weight;
    v4f w1 = *(const v4f*)(weight + 4);
    float b = bias[0];
    if (u0 + 2 <= N) {
        float r0 = residues[u0], r1 = residues[u0 + 1];
        int pre0 = tpre[u0],  pre1 = tpre[u0 + 1];
        int pos0 = tpost[u0], pos1 = tpost[u0 + 1];
        v4f a00 = *(const v4f*)(attrs + (size_t)u0 * 8);
        v4f a01 = *(const v4f*)(attrs + (size_t)u0 * 8 + 4);
        v4f a10 = *(const v4f*)(attrs + (size_t)u0 * 8 + 8);
        v4f a11 = *(const v4f*)(attrs + (size_t)u0 * 8 + 12);
        float l0 = a00.x*w0.x + a00.y*w0.y + a00.z*w0.z + a00.w*w0.w +
                   a01.x*w1.x + a01.y*w1.y + a01.z*w1.z + a01.w*w1.w + b;
        float l1 = a10.x*w0.x + a10.y*w0.y + a10.z*w0.z + a10.w*w0.w +
                   a11.x*w1.x + a11.y*w1.y + a11.z*w1.z + a11.w*w1.w + b;
        float f0 = r0 / (1.0f + __expf(-l0));
        float f1 = r1 / (1.0f + __expf(-l1));
        delta[pre0] =  f0; delta[pre1] =  f1;
        delta[pos0] = -f0; delta[pos1] = -f1;
    } else {
        for (int u = u0; u < N; ++u) {
            float logit = b;
            #pragma unroll
            for (int k = 0; k < 8; ++k) logit += attrs[(size_t)u * 8 + k] * weight[k];
            float f = residues[u] / (1.0f + __expf(-logit));
            delta[tpre[u]]  =  f;
            delta[tpost[u]] = -f;
        }
    }
}

// ---------------------------------------------------------------------------
// scan128: single-dispatch inclusive scan. 128 co-resident blocks; each owns
// a contiguous 8192-elem segment. Pass 1: segment sum -> publish (flag,val).
// Lookback: sum all predecessor segment sums (<=127 spin-reads, 2 lane-rounds).
// Pass 2: chunk-serial rescan with running carry. WS poison 0xAA != flag 1,
// so no zero-init dispatch is needed.
__global__ void __launch_bounds__(SCAN_THREADS)
scan128(float* __restrict__ data,
        unsigned long long* __restrict__ state, int T) {
    __shared__ float wavesums[SCAN_THREADS / 64];
    __shared__ float s_carry;
    const int seg  = blockIdx.x;
    const int base0 = seg * SEGLEN;
    const int segEnd = min(base0 + SEGLEN, T);
    const int lane = threadIdx.x & 63, wid = threadIdx.x >> 6;

    // ---- Pass 1: segment sum.
    float acc = 0.0f;
    for (int off = base0 + threadIdx.x * 4; off < segEnd; off += SCHUNK) {
        if (off + 4 <= segEnd) {
            v4f v = *(const v4f*)(data + off);
            acc += v.x + v.y + v.z + v.w;
        } else {
            for (int i = 0; i < 4 && off + i < segEnd; ++i) acc += data[off + i];
        }
    }
    #pragma unroll
    for (int d = 32; d > 0; d >>= 1) acc += __shfl_down(acc, d, 64);
    if (lane == 0) wavesums[wid] = acc;
    __syncthreads();
    if (threadIdx.x == 0) {
        float segsum = wavesums[0] + wavesums[1] + wavesums[2] + wavesums[3];
        __hip_atomic_store(&state[seg], pack_sf(segsum), __ATOMIC_RELEASE,
                           __HIP_MEMORY_SCOPE_AGENT);
    }

    // ---- Lookback: carry = sum of predecessor segment sums.
    if (wid == 0) {
        float c = 0.0f;
        for (int i = lane; i < seg; i += 64) {
            unsigned long long p;
            do {
                p = __hip_atomic_load(&state[i], __ATOMIC_ACQUIRE,
                                      __HIP_MEMORY_SCOPE_AGENT);
            } while ((unsigned)(p >> 32) != 1u);
            c += __uint_as_float((unsigned)(p & 0xffffffffu));
        }
        #pragma unroll
        for (int d = 32; d > 0; d >>= 1) c += __shfl_down(c, d, 64);
        if (lane == 0) s_carry = c;
    }
    __syncthreads();
    float running = s_carry;

    // ---- Pass 2: chunk-serial inclusive rescan with carry.
    for (int cb = base0; cb < segEnd; cb += SCHUNK) {
        int off = cb + threadIdx.x * 4;
        float v[4];
        bool full = (off + 4 <= segEnd);
        if (full) {
            v4f t = *(const v4f*)(data + off);
            v[0]=t.x; v[1]=t.y; v[2]=t.z; v[3]=t.w;
        } else {
            for (int i = 0; i < 4; ++i)
                v[i] = (off + i < segEnd) ? data[off + i] : 0.0f;
        }
        float run = 0.0f;
        #pragma unroll
        for (int i = 0; i < 4; ++i) { run += v[i]; v[i] = run; }
        float tot = run;
        float x = tot;
        #pragma unroll
        for (int d = 1; d < 64; d <<= 1) {
            float y = __shfl_up(x, d, 64);
            if (lane >= d) x += y;
        }
        if (lane == 63) wavesums[wid] = x;
        __syncthreads();
        float woff = 0.0f, chunktot = 0.0f;
        #pragma unroll
        for (int i = 0; i < SCAN_THREADS / 64; ++i) {
            if (i < wid) woff += wavesums[i];
            chunktot += wavesums[i];
        }
        float add = (x - tot) + woff + running;
        if (full) {
            v4f o = { v[0]+add, v[1]+add, v[2]+add, v[3]+add };
            *(v4f*)(data + off) = o;
        } else {
            for (int i = 0; i < 4; ++i)
                if (off + i < segEnd) data[off + i] = v[i] + add;
        }
        running += chunktot;
        __syncthreads();
    }
}

// ---------------------------------------------------------------------------
// K5: vnode[u] = ycum[tpre[u]] — compresses gather working set to 2MB so the
// pixel gather stays L2-resident (R7: fusing this away cost 300MB of HBM).
__global__ void k5_node_values(const float* __restrict__ ycum,
                               const int* __restrict__ tpre,
                               float* __restrict__ vnode, int N) {
    int u0 = (blockIdx.x * blockDim.x + threadIdx.x) * 2;
    if (u0 + 2 <= N) {
        int t0 = tpre[u0], t1 = tpre[u0 + 1];
        float y0 = ycum[t0], y1 = ycum[t1];
        vnode[u0] = y0; vnode[u0 + 1] = y1;
    } else {
        for (int u = u0; u < N; ++u) vnode[u] = ycum[tpre[u]];
    }
}

// ---------------------------------------------------------------------------
// K6: out[p] = vnode[nop[p]]; 4 px/thread, 8192 blocks (best measured config).
__global__ void k6_gather(const float* __restrict__ vnode,
                          const int* __restrict__ nop,
                          float* __restrict__ out, int P) {
    int i = (blockIdx.x * blockDim.x + threadIdx.x) * 4;
    if (i + 4 <= P) {
        v4i n = *(const v4i*)(nop + i);
        v4f o = { vnode[n.x], vnode[n.y], vnode[n.z], vnode[n.w] };
        *(v4f*)(out + i) = o;
    } else {
        for (; i < P; ++i) out[i] = vnode[nop[i]];
    }
}

// ---------------------------------------------------------------------------
// Fallback-tier scan kernels (proven R5 path, used when ws is small).
__global__ void k2_partials(const float* __restrict__ delta,
                            float* __restrict__ partials, int T) {
    __shared__ float sdata[SCAN_THREADS / 64];
    int base = blockIdx.x * CHUNK + threadIdx.x * EPT;
    float s = 0.0f;
    if (base + EPT <= T) {
        v4f v0 = *(const v4f*)(delta + base);
        v4f v1 = *(const v4f*)(delta + base + 4);
        s = v0.x + v0.y + v0.z + v0.w + v1.x + v1.y + v1.z + v1.w;
    } else {
        for (int i = 0; i < EPT; ++i)
            if (base + i < T) s += delta[base + i];
    }
    #pragma unroll
    for (int d = 32; d > 0; d >>= 1) s += __shfl_down(s, d, 64);
    int lane = threadIdx.x & 63, wid = threadIdx.x >> 6;
    if (lane == 0) sdata[wid] = s;
    __syncthreads();
    if (threadIdx.x == 0)
        partials[blockIdx.x] = sdata[0] + sdata[1] + sdata[2] + sdata[3];
}

__global__ void k4_scan_chunks(float* __restrict__ data,
                               const float* __restrict__ partials, int T) {
    __shared__ float wavesums[SCAN_THREADS / 64];
    __shared__ float redsum[SCAN_THREADS / 64];
    int lane = threadIdx.x & 63, wid = threadIdx.x >> 6;
    float c = 0.0f;
    for (int i = threadIdx.x; i < blockIdx.x; i += SCAN_THREADS)
        c += partials[i];
    #pragma unroll
    for (int d = 32; d > 0; d >>= 1) c += __shfl_down(c, d, 64);
    if (lane == 0) redsum[wid] = c;
    int base = blockIdx.x * CHUNK + threadIdx.x * EPT;
    float v[EPT];
    bool full = (base + EPT <= T);
    if (full) {
        v4f v0 = *(const v4f*)(data + base);
        v4f v1 = *(const v4f*)(data + base + 4);
        v[0]=v0.x; v[1]=v0.y; v[2]=v0.z; v[3]=v0.w;
        v[4]=v1.x; v[5]=v1.y; v[6]=v1.z; v[7]=v1.w;
    } else {
        for (int i = 0; i < EPT; ++i)
            v[i] = (base + i < T) ? data[base + i] : 0.0f;
    }
    float run = 0.0f;
    #pragma unroll
    for (int i = 0; i < EPT; ++i) { run += v[i]; v[i] = run; }
    float tot = run;
    float x = tot;
    #pragma unroll
    for (int d = 1; d < 64; d <<= 1) {
        float y = __shfl_up(x, d, 64);
        if (lane >= d) x += y;
    }
    if (lane == 63) wavesums[wid] = x;
    __syncthreads();
    float woff = 0.0f, offset = redsum[0] + redsum[1] + redsum[2] + redsum[3];
    #pragma unroll
    for (int i = 0; i < SCAN_THREADS / 64; ++i)
        if (i < wid) woff += wavesums[i];
    float add = (x - tot) + woff + offset;
    if (full) {
        v4f o0 = { v[0]+add, v[1]+add, v[2]+add, v[3]+add };
        v4f o1 = { v[4]+add, v[5]+add, v[6]+add, v[7]+add };
        *(v4f*)(data + base)     = o0;
        *(v4f*)(data + base + 4) = o1;
    } else {
        for (int i = 0; i < EPT; ++i)
            if (base + i < T) data[base + i] = v[i] + add;
    }
}

extern "C" void kernel_launch(void* const* d_in, const int* in_sizes, int n_in,
                              void* d_out, int out_size, void* d_ws, size_t ws_size,
                              hipStream_t stream) {
    const float* weight   = (const float*)d_in[0];
    const float* bias     = (const float*)d_in[1];
    const float* residues = (const float*)d_in[2];
    const float* attrs    = (const float*)d_in[3];
    const int*   tpre     = (const int*)d_in[4];
    const int*   tpost    = (const int*)d_in[5];
    const int*   nop      = (const int*)d_in[6];
    float* out = (float*)d_out;

    const int N = in_sizes[2];        // 500,000
    const int T = 2 * N;              // 1,000,000
    const int P = out_size;           // 8,388,608

    // Main tier: delta(T) + vnode(N) + scan state(128 u64).
    size_t needMain = (size_t)(T + N) * sizeof(float) + NSEG * 8;
    size_t needMid  = (size_t)(N + 1024) * sizeof(float) + NSEG * 8;

    if (ws_size >= needMain) {
        float* delta = (float*)d_ws;
        float* vnode = delta + T;
        unsigned long long* state = (unsigned long long*)(vnode + N);
        k1_filter_scatter<<<(N / 2 + 255) / 256, 256, 0, stream>>>(
            attrs, weight, bias, residues, tpre, tpost, delta, N);
        scan128<<<NSEG, SCAN_THREADS, 0, stream>>>(delta, state, T);
        k5_node_values<<<(N / 2 + 255) / 256, 256, 0, stream>>>(delta, tpre, vnode, N);
        k6_gather<<<(P / 4 + 255) / 256, 256, 0, stream>>>(vnode, nop, out, P);
    } else {
        // Fallback: delta aliases out; R5's proven 5-kernel path.
        const int numChunks = (T + CHUNK - 1) / CHUNK;
        float *delta = out, *vnode = (float*)d_ws, *partials = vnode + N;
        k1_filter_scatter<<<(N / 2 + 255) / 256, 256, 0, stream>>>(
            attrs, weight, bias, residues, tpre, tpost, delta, N);
        k2_partials<<<numChunks, SCAN_THREADS, 0, stream>>>(delta, partials, T);
        k4_scan_chunks<<<numChunks, SCAN_THREADS, 0, stream>>>(delta, partials, T);
        k5_node_values<<<(N / 2 + 255) / 256, 256, 0, stream>>>(delta, tpre, vnode, N);
        k6_gather<<<(P / 4 + 255) / 256, 256, 0, stream>>>(vnode, nop, out, P);
    }
}